// Round 13
// baseline (247.421 us; speedup 1.0000x reference)
//
#include <hip/hip_runtime.h>
#include <hip/hip_bf16.h>

// ---------------------------------------------------------------------------
// GATsmall: 2x GATConv (8 heads) + GCNConv head. N=50000, E=500000 (+N self
// loops). Round 13: R11 dispatch structure (separate lean kernels — R12's
// block-range merges collapsed occupancy to 25% and cost 40us) + R12's GOOD
// half: GCN matvec fused into agg2 epilogue (gcn_gemm + out2b round-trip
// deleted). 11 dispatches. bf16 MFMA GEMMs, R7 agg structure, fp32 factored
// attention logits, bf16 tables.
// ---------------------------------------------------------------------------

typedef __attribute__((ext_vector_type(8))) short bf16x8;
typedef __attribute__((ext_vector_type(4))) float f32x4;

// ---------------- helpers ----------------

__device__ __forceinline__ float4 bf4_to_f4(uint2 v) {
    float4 r;
    r.x = __uint_as_float((v.x & 0xFFFFu) << 16);
    r.y = __uint_as_float(v.x & 0xFFFF0000u);
    r.z = __uint_as_float((v.y & 0xFFFFu) << 16);
    r.w = __uint_as_float(v.y & 0xFFFF0000u);
    return r;
}

__device__ __forceinline__ ushort f_to_bf(float f) {
    __hip_bfloat16 hb = __float2bfloat16(f);
    return *reinterpret_cast<ushort*>(&hb);
}

#define LRELU_EXP(e) __expf((e) > 0.f ? (e) : 0.2f * (e))

// ---------------- K1: prep (zero deg | x->xb | W1t/W2t | factored attn w) ---

__global__ __launch_bounds__(256) void prep_kernel(
    const float* __restrict__ x,
    const float* __restrict__ W1, const float* __restrict__ as1, const float* __restrict__ ad1,
    const float* __restrict__ W2, const float* __restrict__ as2, const float* __restrict__ ad2,
    ushort* __restrict__ xb, ushort* __restrict__ W1t, ushort* __restrict__ W2t,
    float* __restrict__ w1s, float* __restrict__ w1d,
    float* __restrict__ w2s, float* __restrict__ w2d,
    int* __restrict__ deg, int n) {
    const int tid = blockIdx.x * 256 + threadIdx.x;
    const int NT = gridDim.x * 256;
    for (int i = tid; i < n; i += NT) deg[i] = 0;
    for (int j = tid; j < n * 32; j += NT) {
        int i = j * 4;
        float4 v = *reinterpret_cast<const float4*>(x + i);
        ushort4 u = make_ushort4(f_to_bf(v.x), f_to_bf(v.y), f_to_bf(v.z), f_to_bf(v.w));
        *reinterpret_cast<ushort4*>(xb + i) = u;
    }
    for (int j = tid; j < 32768; j += NT) {          // W1t [256][128]
        int nn = j >> 7, k = j & 127;
        W1t[j] = f_to_bf(W1[(size_t)k * 256 + nn]);
    }
    for (int j = tid; j < 32768; j += NT) {          // W2t [128][256]
        int nn = j >> 8, k = j & 255;
        W2t[j] = f_to_bf(W2[(size_t)k * 128 + nn]);
    }
    for (int j = tid; j < 1024; j += NT) {           // wprep1 K=128 D=32
        int k = j >> 3, h = j & 7;
        const float* wrow = W1 + (size_t)k * 256 + h * 32;
        const float* as = as1 + h * 32;
        const float* ad = ad1 + h * 32;
        float s1 = 0.f, s2 = 0.f;
        #pragma unroll
        for (int d = 0; d < 32; d += 4) {
            float4 wv = *reinterpret_cast<const float4*>(wrow + d);
            float4 av = *reinterpret_cast<const float4*>(as + d);
            float4 dv = *reinterpret_cast<const float4*>(ad + d);
            s1 += wv.x * av.x + wv.y * av.y + wv.z * av.z + wv.w * av.w;
            s2 += wv.x * dv.x + wv.y * dv.y + wv.z * dv.z + wv.w * dv.w;
        }
        w1s[j] = s1; w1d[j] = s2;
    }
    for (int j = tid; j < 2048; j += NT) {           // wprep2 K=256 D=16
        int k = j >> 3, h = j & 7;
        const float* wrow = W2 + (size_t)k * 128 + h * 16;
        const float* as = as2 + h * 16;
        const float* ad = ad2 + h * 16;
        float s1 = 0.f, s2 = 0.f;
        #pragma unroll
        for (int d = 0; d < 16; d += 4) {
            float4 wv = *reinterpret_cast<const float4*>(wrow + d);
            float4 av = *reinterpret_cast<const float4*>(as + d);
            float4 dv = *reinterpret_cast<const float4*>(ad + d);
            s1 += wv.x * av.x + wv.y * av.y + wv.z * av.z + wv.w * av.w;
            s2 += wv.x * dv.x + wv.y * dv.y + wv.z * dv.z + wv.w * dv.w;
        }
        w2s[j] = s1; w2d[j] = s2;
    }
}

// ---------------- K2: hist + adots1 (both independent) ----------------------

__global__ __launch_bounds__(256) void hist_adots_kernel(
    const int* __restrict__ ei, int E, int Etot, int* __restrict__ deg,
    const ushort* __restrict__ xb,
    const float* __restrict__ w1s, const float* __restrict__ w1d,
    float* __restrict__ a_s, float* __restrict__ a_d, int n) {
    const int tid = blockIdx.x * 256 + threadIdx.x;
    const int NT = gridDim.x * 256;
    for (int e = tid; e < Etot; e += NT) {
        int d = (e < E) ? ei[E + e] : (e - E);
        atomicAdd(&deg[d], 1);
    }
    for (int j = tid; j < n * 8; j += NT) {
        int node = j >> 3, h = j & 7;
        const ushort* xp = xb + (size_t)node * 128;
        float s1 = 0.f, s2 = 0.f;
        #pragma unroll 4
        for (int k = 0; k < 128; k += 8) {
            uint4 v = *reinterpret_cast<const uint4*>(xp + k);
            float4 x0 = bf4_to_f4(make_uint2(v.x, v.y));
            float4 x1 = bf4_to_f4(make_uint2(v.z, v.w));
            s1 += x0.x * w1s[(k + 0) * 8 + h] + x0.y * w1s[(k + 1) * 8 + h] +
                  x0.z * w1s[(k + 2) * 8 + h] + x0.w * w1s[(k + 3) * 8 + h] +
                  x1.x * w1s[(k + 4) * 8 + h] + x1.y * w1s[(k + 5) * 8 + h] +
                  x1.z * w1s[(k + 6) * 8 + h] + x1.w * w1s[(k + 7) * 8 + h];
            s2 += x0.x * w1d[(k + 0) * 8 + h] + x0.y * w1d[(k + 1) * 8 + h] +
                  x0.z * w1d[(k + 2) * 8 + h] + x0.w * w1d[(k + 3) * 8 + h] +
                  x1.x * w1d[(k + 4) * 8 + h] + x1.y * w1d[(k + 5) * 8 + h] +
                  x1.z * w1d[(k + 6) * 8 + h] + x1.w * w1d[(k + 7) * 8 + h];
        }
        a_s[j] = s1;
        a_d[j] = s2;
    }
}

// ---------------- K3: per-chunk inclusive scan of deg -----------------------

__global__ __launch_bounds__(256) void scanA_kernel(const int* __restrict__ deg,
                                                    int* __restrict__ off,
                                                    int* __restrict__ bsum, int n) {
    __shared__ int buf[256];
    int t = threadIdx.x;
    int i = blockIdx.x * 256 + t;
    int v = (i < n) ? deg[i] : 0;
    buf[t] = v;
    __syncthreads();
    #pragma unroll
    for (int st = 1; st < 256; st <<= 1) {
        int x = (t >= st) ? buf[t - st] : 0;
        __syncthreads();
        buf[t] += x;
        __syncthreads();
    }
    if (i < n) off[i + 1] = buf[t];
    if (t == 255) bsum[blockIdx.x] = buf[255];
}

// ---------------- K4: scanC with in-block bsum prefix -----------------------

__global__ __launch_bounds__(256) void scanC_kernel(const int* __restrict__ deg,
                                                    int* __restrict__ off,
                                                    const int* __restrict__ bsum,
                                                    int* __restrict__ cur,
                                                    float* __restrict__ dinv, int n) {
    __shared__ int sred[256];
    const int bid = blockIdx.x;
    const int t = threadIdx.x;
    sred[t] = (t < bid) ? bsum[t] : 0;  // bid < nch <= 256
    __syncthreads();
    #pragma unroll
    for (int st = 128; st > 0; st >>= 1) {
        if (t < st) sred[t] += sred[t + st];
        __syncthreads();
    }
    const int pre = sred[0];
    int i = bid * 256 + t;
    if (i < n) {
        int o = off[i + 1] + pre;
        off[i + 1] = o;
        int d = deg[i];
        cur[i] = o - d;
        dinv[i] = rsqrtf((float)d);  // deg >= 1 (self loop)
    }
    if (i == 0) off[0] = 0;
}

// ---------------- K5: scatter (lean, own dispatch) --------------------------

__global__ __launch_bounds__(256) void scatter_kernel(const int* __restrict__ ei, int E, int Etot,
                                                      int* __restrict__ cur,
                                                      int* __restrict__ ssrc) {
    int e = blockIdx.x * 256 + threadIdx.x;
    if (e >= Etot) return;
    int s, d;
    if (e < E) { s = ei[e]; d = ei[E + e]; }
    else       { s = e - E; d = e - E; }
    int pos = atomicAdd(&cur[d], 1);
    ssrc[pos] = s;
}

// ---------------- adots (layer 2) ----------------

template <int K>
__global__ __launch_bounds__(256) void adots_kernel(const ushort* __restrict__ Xb,
                                                    const float* __restrict__ ws,
                                                    const float* __restrict__ wd,
                                                    float* __restrict__ a_s,
                                                    float* __restrict__ a_d, int n) {
    int gid = blockIdx.x * 256 + threadIdx.x;
    if (gid >= n * 8) return;
    int node = gid >> 3, h = gid & 7;
    const ushort* xp = Xb + (size_t)node * K;
    float s1 = 0.f, s2 = 0.f;
    #pragma unroll 4
    for (int k = 0; k < K; k += 8) {
        uint4 v = *reinterpret_cast<const uint4*>(xp + k);
        float4 x0 = bf4_to_f4(make_uint2(v.x, v.y));
        float4 x1 = bf4_to_f4(make_uint2(v.z, v.w));
        s1 += x0.x * ws[(k + 0) * 8 + h] + x0.y * ws[(k + 1) * 8 + h] +
              x0.z * ws[(k + 2) * 8 + h] + x0.w * ws[(k + 3) * 8 + h] +
              x1.x * ws[(k + 4) * 8 + h] + x1.y * ws[(k + 5) * 8 + h] +
              x1.z * ws[(k + 6) * 8 + h] + x1.w * ws[(k + 7) * 8 + h];
        s2 += x0.x * wd[(k + 0) * 8 + h] + x0.y * wd[(k + 1) * 8 + h] +
              x0.z * wd[(k + 2) * 8 + h] + x0.w * wd[(k + 3) * 8 + h] +
              x1.x * wd[(k + 4) * 8 + h] + x1.y * wd[(k + 5) * 8 + h] +
              x1.z * wd[(k + 6) * 8 + h] + x1.w * wd[(k + 7) * 8 + h];
    }
    a_s[gid] = s1;
    a_d[gid] = s2;
}

// ---------------- bf16 MFMA GEMM: Cb[M,NC] = Ab[M,K] @ Bt[NC,K]^T -----------

template <int K, int NC, int BN>
__global__ __launch_bounds__(256) void mfma_gemm_kernel(const ushort* __restrict__ Ab,
                                                        const ushort* __restrict__ Bt,
                                                        ushort* __restrict__ Cb, int M) {
    constexpr int BM = 128, BK = 32;
    constexpr int FN = BN / 32;
    __shared__ ushort As[BM * BK];
    __shared__ ushort Bs[BN * BK];
    const int tid = threadIdx.x;
    const int lane = tid & 63;
    const int wid = tid >> 6;
    const int bm = blockIdx.y * BM;
    const int bn = blockIdx.x * BN;
    const int wm = (wid >> 1) * 64;
    const int wn = (wid & 1) * (BN / 2);
    const int l15 = lane & 15;
    const int l4 = lane >> 4;
    f32x4 zero4 = {0.f, 0.f, 0.f, 0.f};
    f32x4 acc[4][FN];
    #pragma unroll
    for (int i = 0; i < 4; ++i)
        #pragma unroll
        for (int j = 0; j < FN; ++j) acc[i][j] = zero4;

    for (int k0 = 0; k0 < K; k0 += BK) {
        #pragma unroll
        for (int p = 0; p < 2; ++p) {
            int ci = tid + p * 256;
            int r = ci >> 2, c = ci & 3;
            int row = bm + r;
            uint4 v = make_uint4(0, 0, 0, 0);
            if (row < M) v = *reinterpret_cast<const uint4*>(&Ab[(size_t)row * K + k0 + c * 8]);
            *reinterpret_cast<uint4*>(&As[r * BK + c * 8]) = v;
        }
        #pragma unroll
        for (int p = 0; p < BN / 64; ++p) {
            int ci = tid + p * 256;
            int r = ci >> 2, c = ci & 3;
            uint4 v = *reinterpret_cast<const uint4*>(&Bt[(size_t)(bn + r) * K + k0 + c * 8]);
            *reinterpret_cast<uint4*>(&Bs[r * BK + c * 8]) = v;
        }
        __syncthreads();
        bf16x8 af[4], bfr[FN];
        #pragma unroll
        for (int i = 0; i < 4; ++i)
            af[i] = *reinterpret_cast<const bf16x8*>(&As[(wm + 16 * i + l15) * BK + l4 * 8]);
        #pragma unroll
        for (int j = 0; j < FN; ++j)
            bfr[j] = *reinterpret_cast<const bf16x8*>(&Bs[(wn + 16 * j + l15) * BK + l4 * 8]);
        #pragma unroll
        for (int i = 0; i < 4; ++i)
            #pragma unroll
            for (int j = 0; j < FN; ++j)
                acc[i][j] = __builtin_amdgcn_mfma_f32_16x16x32_bf16(af[i], bfr[j], acc[i][j], 0, 0, 0);
        __syncthreads();
    }
    #pragma unroll
    for (int i = 0; i < 4; ++i) {
        #pragma unroll
        for (int p = 0; p < 4; ++p) {
            int row = bm + wm + 16 * i + l4 * 4 + p;
            if (row < M) {
                #pragma unroll
                for (int j = 0; j < FN; ++j) {
                    Cb[(size_t)row * NC + bn + wn + 16 * j + l15] = f_to_bf(acc[i][j][p]);
                }
            }
        }
    }
}

// ---------------- K7: fused GAT agg layer 1 (R7 structure, proven 51us) -----

template <int C, int DH>
__global__ __launch_bounds__(256) void gat_agg_kernel(const ushort* __restrict__ hfeat,
                                                      const float* __restrict__ a_src,
                                                      const float* __restrict__ a_dst,
                                                      const int* __restrict__ off,
                                                      const int* __restrict__ ssrc,
                                                      const float* __restrict__ bias,
                                                      ushort* __restrict__ outb, int n) {
    constexpr int LPN = C / 4;
    constexpr int GS = DH / 4;
    const int node = blockIdx.x * (256 / LPN) + threadIdx.x / LPN;
    if (node >= n) return;
    const int local = threadIdx.x & (LPN - 1);
    const int c0 = local * 4;
    const int h = c0 / DH;
    const int subl = local & (GS - 1);
    const float adst = a_dst[node * 8 + h];
    const int o0 = off[node], o1 = off[node + 1];
    float ax = 0.f, ay = 0.f, az = 0.f, aw = 0.f, ssum = 0.f;
    int i = o0;
    const int nfull = o0 + ((o1 - o0) / GS) * GS;
    for (; i < nfull; i += GS) {
        int smy = ssrc[i + subl];
        float e = a_src[smy * 8 + h] + adst;
        float evmy = LRELU_EXP(e);
        int sj[GS];
        #pragma unroll
        for (int j = 0; j < GS; ++j) sj[j] = __shfl(smy, j, GS);
        uint2 rv[GS];
        #pragma unroll
        for (int j = 0; j < GS; ++j)
            rv[j] = *reinterpret_cast<const uint2*>(&hfeat[(size_t)sj[j] * C + c0]);
        #pragma unroll
        for (int j = 0; j < GS; ++j) {
            float ev = __shfl(evmy, j, GS);
            float4 hv = bf4_to_f4(rv[j]);
            ssum += ev;
            ax += ev * hv.x; ay += ev * hv.y; az += ev * hv.z; aw += ev * hv.w;
        }
    }
    for (; i < o1; ++i) {
        int s = ssrc[i];
        float e = a_src[s * 8 + h] + adst;
        float v = LRELU_EXP(e);
        uint2 rvv = *reinterpret_cast<const uint2*>(&hfeat[(size_t)s * C + c0]);
        float4 hv = bf4_to_f4(rvv);
        ssum += v;
        ax += v * hv.x; ay += v * hv.y; az += v * hv.z; aw += v * hv.w;
    }
    float sinv = 1.f / (ssum + 1e-16f);
    float4 bb = *reinterpret_cast<const float4*>(bias + c0);
    float ox = fmaxf(ax * sinv + bb.x, 0.f);
    float oy = fmaxf(ay * sinv + bb.y, 0.f);
    float oz = fmaxf(az * sinv + bb.z, 0.f);
    float ow = fmaxf(aw * sinv + bb.w, 0.f);
    ushort4 u = make_ushort4(f_to_bf(ox), f_to_bf(oy), f_to_bf(oz), f_to_bf(ow));
    *reinterpret_cast<ushort4*>(&outb[(size_t)node * C + c0]) = u;
}

// ---------------- K10: agg layer 2 + GCN matvec fused (kept from R12) -------

__global__ __launch_bounds__(256) void gat_agg2_gcn_kernel(
    const ushort* __restrict__ hfeat,
    const float* __restrict__ a_src, const float* __restrict__ a_dst,
    const int* __restrict__ off, const int* __restrict__ ssrc,
    const float* __restrict__ bias, const float* __restrict__ Wg,
    const float* __restrict__ dinv, float* __restrict__ g, int n) {
    constexpr int C = 128, DH = 16;
    constexpr int LPN = C / 4;   // 32 lanes per node
    constexpr int GS = DH / 4;   // 4
    __shared__ float Wsh[128 * 8];
    for (int i = threadIdx.x; i < 1024; i += 256) Wsh[i] = Wg[i];
    __syncthreads();
    const int node = blockIdx.x * (256 / LPN) + threadIdx.x / LPN;
    if (node >= n) return;
    const int local = threadIdx.x & (LPN - 1);
    const int c0 = local * 4;
    const int h = c0 / DH;
    const int subl = local & (GS - 1);
    const float adst = a_dst[node * 8 + h];
    const int o0 = off[node], o1 = off[node + 1];
    float ax = 0.f, ay = 0.f, az = 0.f, aw = 0.f, ssum = 0.f;
    int i = o0;
    const int nfull = o0 + ((o1 - o0) / GS) * GS;
    for (; i < nfull; i += GS) {
        int smy = ssrc[i + subl];
        float e = a_src[smy * 8 + h] + adst;
        float evmy = LRELU_EXP(e);
        int sj[GS];
        #pragma unroll
        for (int j = 0; j < GS; ++j) sj[j] = __shfl(smy, j, GS);
        uint2 rv[GS];
        #pragma unroll
        for (int j = 0; j < GS; ++j)
            rv[j] = *reinterpret_cast<const uint2*>(&hfeat[(size_t)sj[j] * C + c0]);
        #pragma unroll
        for (int j = 0; j < GS; ++j) {
            float ev = __shfl(evmy, j, GS);
            float4 hv = bf4_to_f4(rv[j]);
            ssum += ev;
            ax += ev * hv.x; ay += ev * hv.y; az += ev * hv.z; aw += ev * hv.w;
        }
    }
    for (; i < o1; ++i) {
        int s = ssrc[i];
        float e = a_src[s * 8 + h] + adst;
        float v = LRELU_EXP(e);
        uint2 rvv = *reinterpret_cast<const uint2*>(&hfeat[(size_t)s * C + c0]);
        float4 hv = bf4_to_f4(rvv);
        ssum += v;
        ax += v * hv.x; ay += v * hv.y; az += v * hv.z; aw += v * hv.w;
    }
    float sinv = 1.f / (ssum + 1e-16f);
    float4 bb = *reinterpret_cast<const float4*>(bias + c0);
    float ox = fmaxf(ax * sinv + bb.x, 0.f);
    float oy = fmaxf(ay * sinv + bb.y, 0.f);
    float oz = fmaxf(az * sinv + bb.z, 0.f);
    float ow = fmaxf(aw * sinv + bb.w, 0.f);
    // GCN matvec: p[j] = sum_c out2[c]*Wg[c][j]; per-lane partial, 5-step reduce
    float p[8];
    #pragma unroll
    for (int j = 0; j < 8; ++j)
        p[j] = ox * Wsh[(c0 + 0) * 8 + j] + oy * Wsh[(c0 + 1) * 8 + j] +
               oz * Wsh[(c0 + 2) * 8 + j] + ow * Wsh[(c0 + 3) * 8 + j];
    #pragma unroll
    for (int m = 1; m < LPN; m <<= 1) {
        #pragma unroll
        for (int j = 0; j < 8; ++j) p[j] += __shfl_xor(p[j], m);
    }
    if (local == 0) {
        float dv = dinv[node];
        *reinterpret_cast<float4*>(&g[node * 8]) = make_float4(p[0] * dv, p[1] * dv, p[2] * dv, p[3] * dv);
        *reinterpret_cast<float4*>(&g[node * 8 + 4]) = make_float4(p[4] * dv, p[5] * dv, p[6] * dv, p[7] * dv);
    }
}

// ---------------- K11: GCN aggregation ----------------

__global__ __launch_bounds__(256) void gcn_agg_kernel(const float* __restrict__ g,
                                                      const float* __restrict__ dinv,
                                                      const int* __restrict__ off,
                                                      const int* __restrict__ ssrc,
                                                      const float* __restrict__ bg,
                                                      float* __restrict__ outp, int n) {
    int gid = blockIdx.x * 256 + threadIdx.x;
    if (gid >= n * 8) return;
    int node = gid >> 3, c = gid & 7;
    int o0 = off[node], o1 = off[node + 1];
    float acc = 0.f;
    for (int i = o0; i < o1; ++i) {
        int s = ssrc[i];
        acc += g[(size_t)s * 8 + c];   // dinv[s] pre-folded
    }
    outp[gid] = acc * dinv[node] + bg[c];
}

// ---------------- launch ----------------

extern "C" void kernel_launch(void* const* d_in, const int* in_sizes, int n_in,
                              void* d_out, int out_size, void* d_ws, size_t ws_size,
                              hipStream_t stream) {
    const float* x      = (const float*)d_in[0];
    const int*   ei     = (const int*)d_in[1];
    const float* W1     = (const float*)d_in[2];
    const float* att_s1 = (const float*)d_in[3];
    const float* att_d1 = (const float*)d_in[4];
    const float* b1     = (const float*)d_in[5];
    const float* W2     = (const float*)d_in[6];
    const float* att_s2 = (const float*)d_in[7];
    const float* att_d2 = (const float*)d_in[8];
    const float* b2     = (const float*)d_in[9];
    const float* Wg     = (const float*)d_in[10];
    const float* bg     = (const float*)d_in[11];
    float* out = (float*)d_out;

    const int n    = in_sizes[0] / 128;  // 50000
    const int E    = in_sizes[1] / 2;    // 500000
    const int Etot = E + n;              // 550000

    // workspace carve-up (~70 MB), with region reuse:
    //   regA: h1b bf16 [n,256]               (dead after agg1)
    //   regC: xb  bf16 [n,128] -> h2b bf16   (xb dead after gemm1)
    float*  wsp   = (float*)d_ws;
    float*  regA  = wsp;                              // [n*128] floats
    float*  regB  = regA + (size_t)n * 128;           // [n*128]: out1b bf16 [n,256]
    float*  regC  = regB + (size_t)n * 128;           // [n*64]
    float*  a_s   = regC + (size_t)n * 64;            // [n*8]
    float*  a_d   = a_s + (size_t)n * 8;              // [n*8]
    float*  g     = a_d + (size_t)n * 8;              // [n*8]
    float*  dinv  = g + (size_t)n * 8;                // [n]
    float*  w1s   = dinv + n;                         // [1024]
    float*  w1d   = w1s + 1024;                       // [1024]
    float*  w2s   = w1d + 1024;                       // [2048]
    float*  w2d   = w2s + 2048;                       // [2048]
    float*  w1t_f = w2d + 2048;                       // W1t bf16 [256][128]
    float*  w2t_f = w1t_f + 16384;                    // W2t bf16 [128][256]
    int*    off   = (int*)(w2t_f + 16384);            // [n+1]
    int*    deg   = off + (n + 1);                    // [n]
    int*    cur   = deg + n;                          // [n]
    int*    ssrc  = cur + n;                          // [Etot]
    int*    bsum  = ssrc + Etot;                      // [<=256]

    ushort* h1b   = (ushort*)regA;
    ushort* out1b = (ushort*)regB;
    ushort* xb    = (ushort*)regC;
    ushort* h2b   = (ushort*)regC;
    ushort* W1t   = (ushort*)w1t_f;
    ushort* W2t   = (ushort*)w2t_f;

    const dim3 b256(256);
    const int nch = (n + 255) / 256;

    // CSR + prep + attn logits layer 1
    prep_kernel<<<2048, b256, 0, stream>>>(x, W1, att_s1, att_d1, W2, att_s2, att_d2,
                                           xb, W1t, W2t, w1s, w1d, w2s, w2d, deg, n);
    hist_adots_kernel<<<2048, b256, 0, stream>>>(ei, E, Etot, deg, xb, w1s, w1d, a_s, a_d, n);
    scanA_kernel<<<nch, b256, 0, stream>>>(deg, off, bsum, n);
    scanC_kernel<<<nch, b256, 0, stream>>>(deg, off, bsum, cur, dinv, n);
    scatter_kernel<<<(Etot + 255) / 256, b256, 0, stream>>>(ei, E, Etot, cur, ssrc);

    // layer 1: GAT(128 -> 8x32)
    mfma_gemm_kernel<128, 256, 128><<<dim3(2, (n + 127) / 128), b256, 0, stream>>>(xb, W1t, h1b, n);
    gat_agg_kernel<256, 32><<<(n + 3) / 4, b256, 0, stream>>>(h1b, a_s, a_d, off, ssrc, b1, out1b, n);

    // layer 2: GAT(256 -> 8x16)
    adots_kernel<256><<<(n * 8 + 255) / 256, b256, 0, stream>>>(out1b, w2s, w2d, a_s, a_d, n);
    mfma_gemm_kernel<256, 128, 64><<<dim3(2, (n + 127) / 128), b256, 0, stream>>>(out1b, W2t, h2b, n);

    // agg2 + GCN matvec fused (out2b round-trip eliminated)
    gat_agg2_gcn_kernel<<<(n + 7) / 8, b256, 0, stream>>>(h2b, a_s, a_d, off, ssrc, b2, Wg, dinv, g, n);

    // GCN aggregation
    gcn_agg_kernel<<<(n * 8 + 255) / 256, b256, 0, stream>>>(g, dinv, off, ssrc, bg, out, n);
}

// Round 14
// 241.557 us; speedup vs baseline: 1.0243x; 1.0243x over previous
//
#include <hip/hip_runtime.h>
#include <hip/hip_bf16.h>

// ---------------------------------------------------------------------------
// GATsmall: 2x GATConv (8 heads) + GCNConv head. N=50000, E=500000 (+N self
// loops). Round 14: EXACT R11 structure (best measured: 241.1us, 12
// dispatches) + ONE change: software-pipelined agg inner loop (next
// iteration's ssrc/a_src issued before current FMA consume, hiding the
// chained-load latency). bf16 MFMA GEMMs, fp32 factored attention logits,
// bf16 tables, dinv folded into gcn_gemm.
// ---------------------------------------------------------------------------

typedef __attribute__((ext_vector_type(8))) short bf16x8;
typedef __attribute__((ext_vector_type(4))) float f32x4;

// ---------------- helpers ----------------

__device__ __forceinline__ float4 bf4_to_f4(uint2 v) {
    float4 r;
    r.x = __uint_as_float((v.x & 0xFFFFu) << 16);
    r.y = __uint_as_float(v.x & 0xFFFF0000u);
    r.z = __uint_as_float((v.y & 0xFFFFu) << 16);
    r.w = __uint_as_float(v.y & 0xFFFF0000u);
    return r;
}

__device__ __forceinline__ ushort f_to_bf(float f) {
    __hip_bfloat16 hb = __float2bfloat16(f);
    return *reinterpret_cast<ushort*>(&hb);
}

#define LRELU_EXP(e) __expf((e) > 0.f ? (e) : 0.2f * (e))

// ---------------- K1: prep (zero deg | x->xb | W1t/W2t | factored attn w) ---

__global__ __launch_bounds__(256) void prep_kernel(
    const float* __restrict__ x,
    const float* __restrict__ W1, const float* __restrict__ as1, const float* __restrict__ ad1,
    const float* __restrict__ W2, const float* __restrict__ as2, const float* __restrict__ ad2,
    ushort* __restrict__ xb, ushort* __restrict__ W1t, ushort* __restrict__ W2t,
    float* __restrict__ w1s, float* __restrict__ w1d,
    float* __restrict__ w2s, float* __restrict__ w2d,
    int* __restrict__ deg, int n) {
    const int tid = blockIdx.x * 256 + threadIdx.x;
    const int NT = gridDim.x * 256;
    for (int i = tid; i < n; i += NT) deg[i] = 0;
    for (int j = tid; j < n * 32; j += NT) {
        int i = j * 4;
        float4 v = *reinterpret_cast<const float4*>(x + i);
        ushort4 u = make_ushort4(f_to_bf(v.x), f_to_bf(v.y), f_to_bf(v.z), f_to_bf(v.w));
        *reinterpret_cast<ushort4*>(xb + i) = u;
    }
    for (int j = tid; j < 32768; j += NT) {          // W1t [256][128]
        int nn = j >> 7, k = j & 127;
        W1t[j] = f_to_bf(W1[(size_t)k * 256 + nn]);
    }
    for (int j = tid; j < 32768; j += NT) {          // W2t [128][256]
        int nn = j >> 8, k = j & 255;
        W2t[j] = f_to_bf(W2[(size_t)k * 128 + nn]);
    }
    for (int j = tid; j < 1024; j += NT) {           // wprep1 K=128 D=32
        int k = j >> 3, h = j & 7;
        const float* wrow = W1 + (size_t)k * 256 + h * 32;
        const float* as = as1 + h * 32;
        const float* ad = ad1 + h * 32;
        float s1 = 0.f, s2 = 0.f;
        #pragma unroll
        for (int d = 0; d < 32; d += 4) {
            float4 wv = *reinterpret_cast<const float4*>(wrow + d);
            float4 av = *reinterpret_cast<const float4*>(as + d);
            float4 dv = *reinterpret_cast<const float4*>(ad + d);
            s1 += wv.x * av.x + wv.y * av.y + wv.z * av.z + wv.w * av.w;
            s2 += wv.x * dv.x + wv.y * dv.y + wv.z * dv.z + wv.w * dv.w;
        }
        w1s[j] = s1; w1d[j] = s2;
    }
    for (int j = tid; j < 2048; j += NT) {           // wprep2 K=256 D=16
        int k = j >> 3, h = j & 7;
        const float* wrow = W2 + (size_t)k * 128 + h * 16;
        const float* as = as2 + h * 16;
        const float* ad = ad2 + h * 16;
        float s1 = 0.f, s2 = 0.f;
        #pragma unroll
        for (int d = 0; d < 16; d += 4) {
            float4 wv = *reinterpret_cast<const float4*>(wrow + d);
            float4 av = *reinterpret_cast<const float4*>(as + d);
            float4 dv = *reinterpret_cast<const float4*>(ad + d);
            s1 += wv.x * av.x + wv.y * av.y + wv.z * av.z + wv.w * av.w;
            s2 += wv.x * dv.x + wv.y * dv.y + wv.z * dv.z + wv.w * dv.w;
        }
        w2s[j] = s1; w2d[j] = s2;
    }
}

// ---------------- K2: hist + adots1 (both independent) ----------------------

__global__ __launch_bounds__(256) void hist_adots_kernel(
    const int* __restrict__ ei, int E, int Etot, int* __restrict__ deg,
    const ushort* __restrict__ xb,
    const float* __restrict__ w1s, const float* __restrict__ w1d,
    float* __restrict__ a_s, float* __restrict__ a_d, int n) {
    const int tid = blockIdx.x * 256 + threadIdx.x;
    const int NT = gridDim.x * 256;
    for (int e = tid; e < Etot; e += NT) {
        int d = (e < E) ? ei[E + e] : (e - E);
        atomicAdd(&deg[d], 1);
    }
    for (int j = tid; j < n * 8; j += NT) {
        int node = j >> 3, h = j & 7;
        const ushort* xp = xb + (size_t)node * 128;
        float s1 = 0.f, s2 = 0.f;
        #pragma unroll 4
        for (int k = 0; k < 128; k += 8) {
            uint4 v = *reinterpret_cast<const uint4*>(xp + k);
            float4 x0 = bf4_to_f4(make_uint2(v.x, v.y));
            float4 x1 = bf4_to_f4(make_uint2(v.z, v.w));
            s1 += x0.x * w1s[(k + 0) * 8 + h] + x0.y * w1s[(k + 1) * 8 + h] +
                  x0.z * w1s[(k + 2) * 8 + h] + x0.w * w1s[(k + 3) * 8 + h] +
                  x1.x * w1s[(k + 4) * 8 + h] + x1.y * w1s[(k + 5) * 8 + h] +
                  x1.z * w1s[(k + 6) * 8 + h] + x1.w * w1s[(k + 7) * 8 + h];
            s2 += x0.x * w1d[(k + 0) * 8 + h] + x0.y * w1d[(k + 1) * 8 + h] +
                  x0.z * w1d[(k + 2) * 8 + h] + x0.w * w1d[(k + 3) * 8 + h] +
                  x1.x * w1d[(k + 4) * 8 + h] + x1.y * w1d[(k + 5) * 8 + h] +
                  x1.z * w1d[(k + 6) * 8 + h] + x1.w * w1d[(k + 7) * 8 + h];
        }
        a_s[j] = s1;
        a_d[j] = s2;
    }
}

// ---------------- K3: per-chunk inclusive scan of deg -----------------------

__global__ __launch_bounds__(256) void scanA_kernel(const int* __restrict__ deg,
                                                    int* __restrict__ off,
                                                    int* __restrict__ bsum, int n) {
    __shared__ int buf[256];
    int t = threadIdx.x;
    int i = blockIdx.x * 256 + t;
    int v = (i < n) ? deg[i] : 0;
    buf[t] = v;
    __syncthreads();
    #pragma unroll
    for (int st = 1; st < 256; st <<= 1) {
        int x = (t >= st) ? buf[t - st] : 0;
        __syncthreads();
        buf[t] += x;
        __syncthreads();
    }
    if (i < n) off[i + 1] = buf[t];
    if (t == 255) bsum[blockIdx.x] = buf[255];
}

// ---------------- K4: scanC with in-block bsum prefix -----------------------

__global__ __launch_bounds__(256) void scanC_kernel(const int* __restrict__ deg,
                                                    int* __restrict__ off,
                                                    const int* __restrict__ bsum,
                                                    int* __restrict__ cur,
                                                    float* __restrict__ dinv, int n) {
    __shared__ int sred[256];
    const int bid = blockIdx.x;
    const int t = threadIdx.x;
    sred[t] = (t < bid) ? bsum[t] : 0;  // bid < nch <= 256
    __syncthreads();
    #pragma unroll
    for (int st = 128; st > 0; st >>= 1) {
        if (t < st) sred[t] += sred[t + st];
        __syncthreads();
    }
    const int pre = sred[0];
    int i = bid * 256 + t;
    if (i < n) {
        int o = off[i + 1] + pre;
        off[i + 1] = o;
        int d = deg[i];
        cur[i] = o - d;
        dinv[i] = rsqrtf((float)d);  // deg >= 1 (self loop)
    }
    if (i == 0) off[0] = 0;
}

// ---------------- K5: scatter ----------------

__global__ __launch_bounds__(256) void scatter_kernel(const int* __restrict__ ei, int E, int Etot,
                                                      int* __restrict__ cur,
                                                      int* __restrict__ ssrc) {
    int e = blockIdx.x * 256 + threadIdx.x;
    if (e >= Etot) return;
    int s, d;
    if (e < E) { s = ei[e]; d = ei[E + e]; }
    else       { s = e - E; d = e - E; }
    int pos = atomicAdd(&cur[d], 1);
    ssrc[pos] = s;
}

// ---------------- adots (layer 2) ----------------

template <int K>
__global__ __launch_bounds__(256) void adots_kernel(const ushort* __restrict__ Xb,
                                                    const float* __restrict__ ws,
                                                    const float* __restrict__ wd,
                                                    float* __restrict__ a_s,
                                                    float* __restrict__ a_d, int n) {
    int gid = blockIdx.x * 256 + threadIdx.x;
    if (gid >= n * 8) return;
    int node = gid >> 3, h = gid & 7;
    const ushort* xp = Xb + (size_t)node * K;
    float s1 = 0.f, s2 = 0.f;
    #pragma unroll 4
    for (int k = 0; k < K; k += 8) {
        uint4 v = *reinterpret_cast<const uint4*>(xp + k);
        float4 x0 = bf4_to_f4(make_uint2(v.x, v.y));
        float4 x1 = bf4_to_f4(make_uint2(v.z, v.w));
        s1 += x0.x * ws[(k + 0) * 8 + h] + x0.y * ws[(k + 1) * 8 + h] +
              x0.z * ws[(k + 2) * 8 + h] + x0.w * ws[(k + 3) * 8 + h] +
              x1.x * ws[(k + 4) * 8 + h] + x1.y * ws[(k + 5) * 8 + h] +
              x1.z * ws[(k + 6) * 8 + h] + x1.w * ws[(k + 7) * 8 + h];
        s2 += x0.x * wd[(k + 0) * 8 + h] + x0.y * wd[(k + 1) * 8 + h] +
              x0.z * wd[(k + 2) * 8 + h] + x0.w * wd[(k + 3) * 8 + h] +
              x1.x * wd[(k + 4) * 8 + h] + x1.y * wd[(k + 5) * 8 + h] +
              x1.z * wd[(k + 6) * 8 + h] + x1.w * wd[(k + 7) * 8 + h];
    }
    a_s[gid] = s1;
    a_d[gid] = s2;
}

// ---------------- bf16 MFMA GEMM: Cb[M,NC] = Ab[M,K] @ Bt[NC,K]^T -----------

template <int K, int NC, int BN>
__global__ __launch_bounds__(256) void mfma_gemm_kernel(const ushort* __restrict__ Ab,
                                                        const ushort* __restrict__ Bt,
                                                        ushort* __restrict__ Cb, int M) {
    constexpr int BM = 128, BK = 32;
    constexpr int FN = BN / 32;
    __shared__ ushort As[BM * BK];
    __shared__ ushort Bs[BN * BK];
    const int tid = threadIdx.x;
    const int lane = tid & 63;
    const int wid = tid >> 6;
    const int bm = blockIdx.y * BM;
    const int bn = blockIdx.x * BN;
    const int wm = (wid >> 1) * 64;
    const int wn = (wid & 1) * (BN / 2);
    const int l15 = lane & 15;
    const int l4 = lane >> 4;
    f32x4 zero4 = {0.f, 0.f, 0.f, 0.f};
    f32x4 acc[4][FN];
    #pragma unroll
    for (int i = 0; i < 4; ++i)
        #pragma unroll
        for (int j = 0; j < FN; ++j) acc[i][j] = zero4;

    for (int k0 = 0; k0 < K; k0 += BK) {
        #pragma unroll
        for (int p = 0; p < 2; ++p) {
            int ci = tid + p * 256;
            int r = ci >> 2, c = ci & 3;
            int row = bm + r;
            uint4 v = make_uint4(0, 0, 0, 0);
            if (row < M) v = *reinterpret_cast<const uint4*>(&Ab[(size_t)row * K + k0 + c * 8]);
            *reinterpret_cast<uint4*>(&As[r * BK + c * 8]) = v;
        }
        #pragma unroll
        for (int p = 0; p < BN / 64; ++p) {
            int ci = tid + p * 256;
            int r = ci >> 2, c = ci & 3;
            uint4 v = *reinterpret_cast<const uint4*>(&Bt[(size_t)(bn + r) * K + k0 + c * 8]);
            *reinterpret_cast<uint4*>(&Bs[r * BK + c * 8]) = v;
        }
        __syncthreads();
        bf16x8 af[4], bfr[FN];
        #pragma unroll
        for (int i = 0; i < 4; ++i)
            af[i] = *reinterpret_cast<const bf16x8*>(&As[(wm + 16 * i + l15) * BK + l4 * 8]);
        #pragma unroll
        for (int j = 0; j < FN; ++j)
            bfr[j] = *reinterpret_cast<const bf16x8*>(&Bs[(wn + 16 * j + l15) * BK + l4 * 8]);
        #pragma unroll
        for (int i = 0; i < 4; ++i)
            #pragma unroll
            for (int j = 0; j < FN; ++j)
                acc[i][j] = __builtin_amdgcn_mfma_f32_16x16x32_bf16(af[i], bfr[j], acc[i][j], 0, 0, 0);
        __syncthreads();
    }
    #pragma unroll
    for (int i = 0; i < 4; ++i) {
        #pragma unroll
        for (int p = 0; p < 4; ++p) {
            int row = bm + wm + 16 * i + l4 * 4 + p;
            if (row < M) {
                #pragma unroll
                for (int j = 0; j < FN; ++j) {
                    Cb[(size_t)row * NC + bn + wn + 16 * j + l15] = f_to_bf(acc[i][j][p]);
                }
            }
        }
    }
}

// ---------------- fused GAT aggregation (R7 layout + SW pipeline) -----------
// C/4 lanes per node; GS = DH/4 lanes share one head. NEW: next iteration's
// ssrc + a_src loads are issued BEFORE the current iteration's FMA consume,
// hiding the chained scalar-load latency under the gather wait.

template <int C, int DH>
__global__ __launch_bounds__(256) void gat_agg_kernel(const ushort* __restrict__ hfeat,
                                                      const float* __restrict__ a_src,
                                                      const float* __restrict__ a_dst,
                                                      const int* __restrict__ off,
                                                      const int* __restrict__ ssrc,
                                                      const float* __restrict__ bias,
                                                      ushort* __restrict__ outb, int n) {
    constexpr int LPN = C / 4;   // 64 (layer1) or 32 (layer2) lanes per node
    constexpr int GS = DH / 4;   // 8 (layer1) or 4 (layer2) lanes per head
    const int node = blockIdx.x * (256 / LPN) + threadIdx.x / LPN;
    if (node >= n) return;
    const int local = threadIdx.x & (LPN - 1);
    const int c0 = local * 4;
    const int h = c0 / DH;
    const int subl = local & (GS - 1);
    const float adst = a_dst[node * 8 + h];
    const int o0 = off[node], o1 = off[node + 1];
    float ax = 0.f, ay = 0.f, az = 0.f, aw = 0.f, ssum = 0.f;
    int i = o0;
    const int nfull = o0 + ((o1 - o0) / GS) * GS;
    if (i < nfull) {
        int smy = ssrc[i + subl];
        float emy = a_src[smy * 8 + h];
        while (i < nfull) {
            float evmy = LRELU_EXP(emy + adst);
            int sj[GS];
            #pragma unroll
            for (int j = 0; j < GS; ++j) sj[j] = __shfl(smy, j, GS);
            uint2 rv[GS];
            #pragma unroll
            for (int j = 0; j < GS; ++j)
                rv[j] = *reinterpret_cast<const uint2*>(&hfeat[(size_t)sj[j] * C + c0]);
            i += GS;
            if (i < nfull) {                     // prefetch next iteration
                smy = ssrc[i + subl];
                emy = a_src[smy * 8 + h];
            }
            #pragma unroll
            for (int j = 0; j < GS; ++j) {
                float ev = __shfl(evmy, j, GS);
                float4 hv = bf4_to_f4(rv[j]);
                ssum += ev;
                ax += ev * hv.x; ay += ev * hv.y; az += ev * hv.z; aw += ev * hv.w;
            }
        }
    }
    for (; i < o1; ++i) {
        int s = ssrc[i];
        float e = a_src[s * 8 + h] + adst;
        float v = LRELU_EXP(e);
        uint2 rvv = *reinterpret_cast<const uint2*>(&hfeat[(size_t)s * C + c0]);
        float4 hv = bf4_to_f4(rvv);
        ssum += v;
        ax += v * hv.x; ay += v * hv.y; az += v * hv.z; aw += v * hv.w;
    }
    float sinv = 1.f / (ssum + 1e-16f);
    float4 bb = *reinterpret_cast<const float4*>(bias + c0);
    float ox = fmaxf(ax * sinv + bb.x, 0.f);
    float oy = fmaxf(ay * sinv + bb.y, 0.f);
    float oz = fmaxf(az * sinv + bb.z, 0.f);
    float ow = fmaxf(aw * sinv + bb.w, 0.f);
    ushort4 u = make_ushort4(f_to_bf(ox), f_to_bf(oy), f_to_bf(oz), f_to_bf(ow));
    *reinterpret_cast<ushort4*>(&outb[(size_t)node * C + c0]) = u;
}

// ---------------- GCN head (R11 structure) ----------------

__global__ __launch_bounds__(256) void gcn_gemm_kernel(const ushort* __restrict__ Ab,
                                                       const float* __restrict__ Wg,
                                                       const float* __restrict__ dinv,
                                                       float* __restrict__ g, int n) {
    __shared__ float W[128 * 8];
    for (int i = threadIdx.x; i < 1024; i += 256) W[i] = Wg[i];
    __syncthreads();
    int gid = blockIdx.x * 256 + threadIdx.x;
    if (gid >= n * 8) return;
    int node = gid >> 3, c = gid & 7;
    const ushort* ap = Ab + (size_t)node * 128;
    float acc = 0.f;
    #pragma unroll
    for (int k = 0; k < 128; k += 8) {
        uint4 v = *reinterpret_cast<const uint4*>(ap + k);
        float4 x0 = bf4_to_f4(make_uint2(v.x, v.y));
        float4 x1 = bf4_to_f4(make_uint2(v.z, v.w));
        acc += x0.x * W[(k + 0) * 8 + c] + x0.y * W[(k + 1) * 8 + c] +
               x0.z * W[(k + 2) * 8 + c] + x0.w * W[(k + 3) * 8 + c] +
               x1.x * W[(k + 4) * 8 + c] + x1.y * W[(k + 5) * 8 + c] +
               x1.z * W[(k + 6) * 8 + c] + x1.w * W[(k + 7) * 8 + c];
    }
    g[gid] = acc * dinv[node];
}

__global__ __launch_bounds__(256) void gcn_agg_kernel(const float* __restrict__ g,
                                                      const float* __restrict__ dinv,
                                                      const int* __restrict__ off,
                                                      const int* __restrict__ ssrc,
                                                      const float* __restrict__ bg,
                                                      float* __restrict__ outp, int n) {
    int gid = blockIdx.x * 256 + threadIdx.x;
    if (gid >= n * 8) return;
    int node = gid >> 3, c = gid & 7;
    int o0 = off[node], o1 = off[node + 1];
    float acc = 0.f;
    for (int i = o0; i < o1; ++i) {
        int s = ssrc[i];
        acc += g[(size_t)s * 8 + c];   // dinv[s] pre-folded
    }
    outp[gid] = acc * dinv[node] + bg[c];
}

// ---------------- launch ----------------

extern "C" void kernel_launch(void* const* d_in, const int* in_sizes, int n_in,
                              void* d_out, int out_size, void* d_ws, size_t ws_size,
                              hipStream_t stream) {
    const float* x      = (const float*)d_in[0];
    const int*   ei     = (const int*)d_in[1];
    const float* W1     = (const float*)d_in[2];
    const float* att_s1 = (const float*)d_in[3];
    const float* att_d1 = (const float*)d_in[4];
    const float* b1     = (const float*)d_in[5];
    const float* W2     = (const float*)d_in[6];
    const float* att_s2 = (const float*)d_in[7];
    const float* att_d2 = (const float*)d_in[8];
    const float* b2     = (const float*)d_in[9];
    const float* Wg     = (const float*)d_in[10];
    const float* bg     = (const float*)d_in[11];
    float* out = (float*)d_out;

    const int n    = in_sizes[0] / 128;  // 50000
    const int E    = in_sizes[1] / 2;    // 500000
    const int Etot = E + n;              // 550000

    // workspace carve-up (~70 MB), with region reuse:
    //   regA: h1b bf16 [n,256]  -> out2b bf16 [n,128] (h1b dead after agg1)
    //   regC: xb  bf16 [n,128]  -> h2b  bf16 [n,128]  (xb dead after gemm1)
    float*  wsp   = (float*)d_ws;
    float*  regA  = wsp;                              // [n*128] floats
    float*  regB  = regA + (size_t)n * 128;           // [n*128]: out1b bf16 [n,256]
    float*  regC  = regB + (size_t)n * 128;           // [n*64]
    float*  a_s   = regC + (size_t)n * 64;            // [n*8]
    float*  a_d   = a_s + (size_t)n * 8;              // [n*8]
    float*  g     = a_d + (size_t)n * 8;              // [n*8]
    float*  dinv  = g + (size_t)n * 8;                // [n]
    float*  w1s   = dinv + n;                         // [1024]
    float*  w1d   = w1s + 1024;                       // [1024]
    float*  w2s   = w1d + 1024;                       // [2048]
    float*  w2d   = w2s + 2048;                       // [2048]
    float*  w1t_f = w2d + 2048;                       // W1t bf16 [256][128]
    float*  w2t_f = w1t_f + 16384;                    // W2t bf16 [128][256]
    int*    off   = (int*)(w2t_f + 16384);            // [n+1]
    int*    deg   = off + (n + 1);                    // [n]
    int*    cur   = deg + n;                          // [n]
    int*    ssrc  = cur + n;                          // [Etot]
    int*    bsum  = ssrc + Etot;                      // [<=256]

    ushort* h1b   = (ushort*)regA;
    ushort* out2b = (ushort*)regA;
    ushort* out1b = (ushort*)regB;
    ushort* xb    = (ushort*)regC;
    ushort* h2b   = (ushort*)regC;
    ushort* W1t   = (ushort*)w1t_f;
    ushort* W2t   = (ushort*)w2t_f;

    const dim3 b256(256);
    const int nch = (n + 255) / 256;

    // CSR + prep + attn logits layer 1
    prep_kernel<<<2048, b256, 0, stream>>>(x, W1, att_s1, att_d1, W2, att_s2, att_d2,
                                           xb, W1t, W2t, w1s, w1d, w2s, w2d, deg, n);
    hist_adots_kernel<<<2048, b256, 0, stream>>>(ei, E, Etot, deg, xb, w1s, w1d, a_s, a_d, n);
    scanA_kernel<<<nch, b256, 0, stream>>>(deg, off, bsum, n);
    scanC_kernel<<<nch, b256, 0, stream>>>(deg, off, bsum, cur, dinv, n);
    scatter_kernel<<<(Etot + 255) / 256, b256, 0, stream>>>(ei, E, Etot, cur, ssrc);

    // layer 1: GAT(128 -> 8x32)
    mfma_gemm_kernel<128, 256, 128><<<dim3(2, (n + 127) / 128), b256, 0, stream>>>(xb, W1t, h1b, n);
    gat_agg_kernel<256, 32><<<(n + 3) / 4, b256, 0, stream>>>(h1b, a_s, a_d, off, ssrc, b1, out1b, n);

    // layer 2: GAT(256 -> 8x16)
    adots_kernel<256><<<(n * 8 + 255) / 256, b256, 0, stream>>>(out1b, w2s, w2d, a_s, a_d, n);
    mfma_gemm_kernel<256, 128, 64><<<dim3(2, (n + 127) / 128), b256, 0, stream>>>(out1b, W2t, h2b, n);
    gat_agg_kernel<128, 16><<<(n + 7) / 8, b256, 0, stream>>>(h2b, a_s, a_d, off, ssrc, b2, out2b, n);

    // GCN head
    gcn_gemm_kernel<<<(n * 8 + 255) / 256, b256, 0, stream>>>(out2b, Wg, dinv, g, n);
    gcn_agg_kernel<<<(n * 8 + 255) / 256, b256, 0, stream>>>(g, dinv, off, ssrc, bg, out, n);
}